// Round 1
// baseline (848.331 us; speedup 1.0000x reference)
//
#include <hip/hip_runtime.h>

#define DD 128
#define HH 8
#define DHd 16
#define DFF 512
#define EPS 1e-6f
#define SLOPE 0.2f
#define TN 64

// ---------------- zero int buffer ----------------
__global__ void kzero(int* __restrict__ p, int n) {
    int i = blockIdx.x * blockDim.x + threadIdx.x;
    if (i < n) p[i] = 0;
}

// ---------------- K1: LN1 + x = ln1 @ W_att + a_s/a_d ----------------
__global__ __launch_bounds__(256) void k1_ln_proj(
    const float* __restrict__ nf, const float* __restrict__ g, const float* __restrict__ b,
    const float* __restrict__ W, const float* __restrict__ asrc, const float* __restrict__ adst,
    float* __restrict__ x, float* __restrict__ a_s, float* __restrict__ a_d,
    int n, int npb) {
    __shared__ float WT[DD][132];     // transposed W, padded: b128 rows, 16B-aligned
    __shared__ float lnrow[4][DD];
    __shared__ float psum[16];
    const int tid = threadIdx.x;
    for (int i = tid; i < DD * DD; i += 256) {
        int k = i >> 7, c = i & 127;
        WT[c][k] = W[i];
    }
    const int t  = tid & 127;
    const int p  = tid >> 7;   // node-pair within block iteration
    const int wv = tid >> 6;   // wave id 0..3
    const float gt = g[t], bt = b[t];
    const float at_s = asrc[t], at_d = adst[t];
    const int base = blockIdx.x * npb;
    __syncthreads();
    for (int it = 0; it < npb; it += 4) {
        const int n0 = base + it + 2 * p;
        const int n1 = n0 + 1;
        const bool v0 = n0 < n, v1 = n1 < n;
        float val0 = v0 ? nf[(size_t)n0 * DD + t] : 0.f;
        float val1 = v1 ? nf[(size_t)n1 * DD + t] : 0.f;
        float s0 = val0, s1 = val1;
        #pragma unroll
        for (int o = 32; o >= 1; o >>= 1) { s0 += __shfl_xor(s0, o); s1 += __shfl_xor(s1, o); }
        if ((tid & 63) == 0) { psum[wv] = s0; psum[8 + wv] = s1; }
        __syncthreads();
        const float mean0 = (psum[2 * p] + psum[2 * p + 1]) * (1.f / DD);
        const float mean1 = (psum[8 + 2 * p] + psum[8 + 2 * p + 1]) * (1.f / DD);
        __syncthreads();
        const float d0 = val0 - mean0, d1 = val1 - mean1;
        s0 = d0 * d0; s1 = d1 * d1;
        #pragma unroll
        for (int o = 32; o >= 1; o >>= 1) { s0 += __shfl_xor(s0, o); s1 += __shfl_xor(s1, o); }
        if ((tid & 63) == 0) { psum[wv] = s0; psum[8 + wv] = s1; }
        __syncthreads();
        // two-pass variance, Bessel-corrected: *(D/(D-1))/D = 1/(D-1)
        const float var0 = (psum[2 * p] + psum[2 * p + 1]) * (1.f / (DD - 1));
        const float var1 = (psum[8 + 2 * p] + psum[8 + 2 * p + 1]) * (1.f / (DD - 1));
        const float i0 = 1.f / (sqrtf(var0) + EPS);
        const float i1 = 1.f / (sqrtf(var1) + EPS);
        lnrow[2 * p][t]     = gt * d0 * i0 + bt;
        lnrow[2 * p + 1][t] = gt * d1 * i1 + bt;
        __syncthreads();
        // matmul: this thread computes column t for both nodes of its pair
        float acc0 = 0.f, acc1 = 0.f;
        const float4* lr0 = (const float4*)lnrow[2 * p];
        const float4* lr1 = (const float4*)lnrow[2 * p + 1];
        #pragma unroll 8
        for (int k4 = 0; k4 < 32; ++k4) {
            float4 w4 = *(const float4*)&WT[t][k4 * 4];
            float4 l0 = lr0[k4];
            float4 l1 = lr1[k4];
            acc0 = fmaf(w4.x, l0.x, fmaf(w4.y, l0.y, fmaf(w4.z, l0.z, fmaf(w4.w, l0.w, acc0))));
            acc1 = fmaf(w4.x, l1.x, fmaf(w4.y, l1.y, fmaf(w4.z, l1.z, fmaf(w4.w, l1.w, acc1))));
        }
        if (v0) x[(size_t)n0 * DD + t] = acc0;
        if (v1) x[(size_t)n1 * DD + t] = acc1;
        // per-head attention logits: reduce over 16-lane groups (head = t>>4)
        float as0 = acc0 * at_s, as1 = acc1 * at_s;
        float ad0 = acc0 * at_d, ad1 = acc1 * at_d;
        #pragma unroll
        for (int o = 8; o >= 1; o >>= 1) {
            as0 += __shfl_xor(as0, o); as1 += __shfl_xor(as1, o);
            ad0 += __shfl_xor(ad0, o); ad1 += __shfl_xor(ad1, o);
        }
        if ((t & 15) == 0) {
            int h = t >> 4;
            if (v0) { a_s[n0 * HH + h] = as0; a_d[n0 * HH + h] = ad0; }
            if (v1) { a_s[n1 * HH + h] = as1; a_d[n1 * HH + h] = ad1; }
        }
        __syncthreads();
    }
}

// ---------------- K2: in-degree count ----------------
__global__ void k2_deg(const int* __restrict__ ei, int* __restrict__ deg, int E) {
    int e = blockIdx.x * blockDim.x + threadIdx.x;
    if (e < E) atomicAdd(&deg[ei[E + e]], 1);
}

// ---------------- K3: single-block exclusive scan -> row_ptr, cursor ----------------
__global__ __launch_bounds__(1024) void k3_scan(const int* __restrict__ deg, int* __restrict__ row_ptr,
                                                int* __restrict__ cursor, int n) {
    __shared__ int sm[1024];
    __shared__ int carry;
    if (threadIdx.x == 0) { carry = 0; row_ptr[0] = 0; }
    __syncthreads();
    for (int base = 0; base < n; base += 1024) {
        const int i = base + threadIdx.x;
        const int v = (i < n) ? deg[i] : 0;
        sm[threadIdx.x] = v;
        __syncthreads();
        for (int off = 1; off < 1024; off <<= 1) {
            int tt = (threadIdx.x >= off) ? sm[threadIdx.x - off] : 0;
            __syncthreads();
            sm[threadIdx.x] += tt;
            __syncthreads();
        }
        const int inc = sm[threadIdx.x] + carry;   // inclusive prefix
        if (i < n) { row_ptr[i + 1] = inc; cursor[i] = inc - v; }
        __syncthreads();
        if (threadIdx.x == 0) carry += sm[1023];
        __syncthreads();
    }
}

// ---------------- K4: scatter src ids into CSR ----------------
__global__ void k4_scatter(const int* __restrict__ ei, int* __restrict__ cursor,
                           int* __restrict__ col_src, int E) {
    int e = blockIdx.x * blockDim.x + threadIdx.x;
    if (e < E) {
        int dst = ei[E + e];
        int pos = atomicAdd(&cursor[dst], 1);
        col_src[pos] = ei[e];
    }
}

// ---------------- K5: per-dst online-softmax gather + residual + LN2 ----------------
__global__ __launch_bounds__(256) void k5_gather(
    const float* __restrict__ x, const float* __restrict__ a_s, const float* __restrict__ a_d,
    const int* __restrict__ row_ptr, const int* __restrict__ col_src,
    const float* __restrict__ nf, const float* __restrict__ bias_att,
    const float* __restrict__ ln2g, const float* __restrict__ ln2b,
    float* __restrict__ nf1, float* __restrict__ h2, int n) {
    const int w = (blockIdx.x * blockDim.x + threadIdx.x) >> 6;   // one wave per dst node
    if (w >= n) return;
    const int lane = threadIdx.x & 63;
    const int h = lane >> 3;           // cols 2l,2l+1 -> head = l/8
    const int c0 = lane * 2;
    const float ad = a_d[w * HH + h];
    // self-loop first (PyG adds self-loops; guarantees non-empty segment)
    float e = a_s[w * HH + h] + ad;
    e = e > 0.f ? e : SLOPE * e;
    float m = e;
    float denom = 1.f;
    float2 xv = *(const float2*)&x[(size_t)w * DD + c0];
    float acc0 = xv.x, acc1 = xv.y;
    const int beg = row_ptr[w], end = row_ptr[w + 1];
    for (int j = beg; j < end; ++j) {
        const int src = col_src[j];
        float ev = a_s[src * HH + h] + ad;
        ev = ev > 0.f ? ev : SLOPE * ev;
        const float nm = fmaxf(m, ev);
        const float sc = __expf(m - nm);
        const float pp = __expf(ev - nm);
        float2 xs = *(const float2*)&x[(size_t)src * DD + c0];
        denom = denom * sc + pp;
        acc0 = acc0 * sc + xs.x * pp;
        acc1 = acc1 * sc + xs.y * pp;
        m = nm;
    }
    const float inv = 1.f / (denom + 1e-16f);
    float o0 = acc0 * inv + bias_att[c0]     + nf[(size_t)w * DD + c0];
    float o1 = acc1 * inv + bias_att[c0 + 1] + nf[(size_t)w * DD + c0 + 1];
    *(float2*)&nf1[(size_t)w * DD + c0] = make_float2(o0, o1);
    // fused LN2 (wave holds the whole 128-wide row)
    float s = o0 + o1;
    #pragma unroll
    for (int o = 32; o >= 1; o >>= 1) s += __shfl_xor(s, o);
    const float mean = s * (1.f / DD);
    const float d0 = o0 - mean, d1 = o1 - mean;
    float q = d0 * d0 + d1 * d1;
    #pragma unroll
    for (int o = 32; o >= 1; o >>= 1) q += __shfl_xor(q, o);
    const float var = q * (1.f / (DD - 1));
    const float iv = 1.f / (sqrtf(var) + EPS);
    float z0 = ln2g[c0] * d0 * iv + ln2b[c0];
    float z1 = ln2g[c0 + 1] * d1 * iv + ln2b[c0 + 1];
    *(float2*)&h2[(size_t)w * DD + c0] = make_float2(z0, z1);
}

// ---------------- K6: fused FFN: out = nf1 + relu(h2@W1+b1)@W2 + b2 ----------------
__global__ __launch_bounds__(256) void k6_ffn(
    const float* __restrict__ h2, const float* __restrict__ nf1,
    const float* __restrict__ W1, const float* __restrict__ b1,
    const float* __restrict__ W2, const float* __restrict__ b2,
    float* __restrict__ out, int n) {
    __shared__ float Wbuf[DD][DD];   // 64KB, reused for W1-chunk then W2-chunk
    __shared__ float h2t[DD][68];    // [k][node], padded
    __shared__ float hht[DD][68];
    const int tid = threadIdx.x;
    const int ng = tid >> 5;   // 8 node-groups of 8 nodes
    const int cg = tid & 31;   // 32 col-groups of 4 cols
    const int nbase = blockIdx.x * TN;
    // stage h2 tile transposed (coalesced global read, strided LDS write)
    for (int i = tid; i < TN * 32; i += 256) {
        const int node = i >> 5, kq = i & 31;
        float4 v = make_float4(0.f, 0.f, 0.f, 0.f);
        if (nbase + node < n) v = *(const float4*)&h2[(size_t)(nbase + node) * DD + 4 * kq];
        h2t[4 * kq + 0][node] = v.x;
        h2t[4 * kq + 1][node] = v.y;
        h2t[4 * kq + 2][node] = v.z;
        h2t[4 * kq + 3][node] = v.w;
    }
    float acc2[8][4];
    #pragma unroll
    for (int a = 0; a < 8; ++a)
        #pragma unroll
        for (int c = 0; c < 4; ++c) acc2[a][c] = 0.f;

    for (int ch = 0; ch < 4; ++ch) {
        __syncthreads();   // prev mm2 / h2t staging done
        for (int i = tid; i < DD * 32; i += 256) {
            const int k = i >> 5, q = i & 31;
            *(float4*)&Wbuf[k][4 * q] = *(const float4*)&W1[k * DFF + ch * DD + 4 * q];
        }
        __syncthreads();
        float acc1[8][4];
        #pragma unroll
        for (int a = 0; a < 8; ++a)
            #pragma unroll
            for (int c = 0; c < 4; ++c) acc1[a][c] = 0.f;
        for (int k = 0; k < DD; ++k) {
            float4 ha = *(const float4*)&h2t[k][8 * ng];
            float4 hb = *(const float4*)&h2t[k][8 * ng + 4];
            float4 wv = *(const float4*)&Wbuf[k][4 * cg];
            float hv[8] = {ha.x, ha.y, ha.z, ha.w, hb.x, hb.y, hb.z, hb.w};
            float wa[4] = {wv.x, wv.y, wv.z, wv.w};
            #pragma unroll
            for (int a = 0; a < 8; ++a)
                #pragma unroll
                for (int c = 0; c < 4; ++c) acc1[a][c] = fmaf(hv[a], wa[c], acc1[a][c]);
        }
        const float4 b1v = *(const float4*)&b1[ch * DD + 4 * cg];
        const float bb[4] = {b1v.x, b1v.y, b1v.z, b1v.w};
        __syncthreads();   // Wbuf reads done; prev hht reads done
        #pragma unroll
        for (int c = 0; c < 4; ++c)
            #pragma unroll
            for (int a = 0; a < 8; ++a)
                hht[4 * cg + c][8 * ng + a] = fmaxf(acc1[a][c] + bb[c], 0.f);
        for (int i = tid; i < DD * 32; i += 256) {
            const int k = i >> 5, q = i & 31;
            *(float4*)&Wbuf[k][4 * q] = *(const float4*)&W2[(ch * DD + k) * DD + 4 * q];
        }
        __syncthreads();
        for (int k = 0; k < DD; ++k) {
            float4 ha = *(const float4*)&hht[k][8 * ng];
            float4 hb = *(const float4*)&hht[k][8 * ng + 4];
            float4 wv = *(const float4*)&Wbuf[k][4 * cg];
            float hv[8] = {ha.x, ha.y, ha.z, ha.w, hb.x, hb.y, hb.z, hb.w};
            float wa[4] = {wv.x, wv.y, wv.z, wv.w};
            #pragma unroll
            for (int a = 0; a < 8; ++a)
                #pragma unroll
                for (int c = 0; c < 4; ++c) acc2[a][c] = fmaf(hv[a], wa[c], acc2[a][c]);
        }
    }
    // epilogue: + b2 + residual
    const float4 b2v = *(const float4*)&b2[4 * cg];
    #pragma unroll
    for (int a = 0; a < 8; ++a) {
        const int node = nbase + 8 * ng + a;
        if (node < n) {
            float4 r = *(const float4*)&nf1[(size_t)node * DD + 4 * cg];
            float4 o;
            o.x = acc2[a][0] + b2v.x + r.x;
            o.y = acc2[a][1] + b2v.y + r.y;
            o.z = acc2[a][2] + b2v.z + r.z;
            o.w = acc2[a][3] + b2v.w + r.w;
            *(float4*)&out[(size_t)node * DD + 4 * cg] = o;
        }
    }
}

extern "C" void kernel_launch(void* const* d_in, const int* in_sizes, int n_in,
                              void* d_out, int out_size, void* d_ws, size_t ws_size,
                              hipStream_t stream) {
    const float* nf       = (const float*)d_in[0];
    const int*   ei       = (const int*)d_in[1];
    const float* ln1_g    = (const float*)d_in[2];
    const float* ln1_b    = (const float*)d_in[3];
    const float* W_att    = (const float*)d_in[4];
    const float* att_src  = (const float*)d_in[5];
    const float* att_dst  = (const float*)d_in[6];
    const float* bias_att = (const float*)d_in[7];
    const float* ln2_g    = (const float*)d_in[8];
    const float* ln2_b    = (const float*)d_in[9];
    const float* W1       = (const float*)d_in[10];
    const float* b1       = (const float*)d_in[11];
    const float* W2       = (const float*)d_in[12];
    const float* b2       = (const float*)d_in[13];
    const int n = in_sizes[0] / DD;
    const int E = in_sizes[1] / 2;

    char* ws = (char*)d_ws;
    size_t off = 0;
    auto alloc = [&](size_t bytes) {
        off = (off + 255) & ~(size_t)255;
        char* p = ws + off;
        off += bytes;
        return p;
    };
    float* x       = (float*)alloc((size_t)n * DD * 4);
    float* a_s     = (float*)alloc((size_t)n * HH * 4);
    float* a_d     = (float*)alloc((size_t)n * HH * 4);
    float* nf1     = (float*)alloc((size_t)n * DD * 4);
    float* h2      = (float*)alloc((size_t)n * DD * 4);
    int*   row_ptr = (int*)alloc((size_t)(n + 1) * 4);
    int*   cursor  = (int*)alloc((size_t)n * 4);
    int*   deg     = (int*)alloc((size_t)n * 4);
    int*   col_src = (int*)alloc((size_t)E * 4);
    (void)ws_size; (void)n_in; (void)out_size;

    const int npb = 64;
    kzero<<<(n + 255) / 256, 256, 0, stream>>>(deg, n);
    k1_ln_proj<<<(n + npb - 1) / npb, 256, 0, stream>>>(nf, ln1_g, ln1_b, W_att, att_src, att_dst,
                                                        x, a_s, a_d, n, npb);
    k2_deg<<<(E + 255) / 256, 256, 0, stream>>>(ei, deg, E);
    k3_scan<<<1, 1024, 0, stream>>>(deg, row_ptr, cursor, n);
    k4_scatter<<<(E + 255) / 256, 256, 0, stream>>>(ei, cursor, col_src, E);
    k5_gather<<<(n + 3) / 4, 256, 0, stream>>>(x, a_s, a_d, row_ptr, col_src, nf, bias_att,
                                               ln2_g, ln2_b, nf1, h2, n);
    k6_ffn<<<(n + TN - 1) / TN, 256, 0, stream>>>(h2, nf1, W1, b1, W2, b2, (float*)d_out, n);
}

// Round 2
// 478.757 us; speedup vs baseline: 1.7719x; 1.7719x over previous
//
#include <hip/hip_runtime.h>

#define DD 128
#define HH 8
#define DFF 512
#define EPS 1e-6f
#define SLOPE 0.2f
#define TM 64

typedef float f32x4 __attribute__((ext_vector_type(4)));
typedef short bf16x8 __attribute__((ext_vector_type(8)));

__device__ __forceinline__ ushort f2bf(float f) {
    unsigned u = __float_as_uint(f);
    return (ushort)((u + 0x7FFFu + ((u >> 16) & 1u)) >> 16);   // RNE
}
__device__ __forceinline__ float bf2f(ushort h) {
    return __uint_as_float(((unsigned)h) << 16);
}

// ---------------- zero int buffer ----------------
__global__ void kzero(int* __restrict__ p, int n) {
    int i = blockIdx.x * blockDim.x + threadIdx.x;
    if (i < n) p[i] = 0;
}

// ---------------- prep: transpose + split fp32 -> bf16 hi/lo ----------------
// src [R][C] fp32  ->  hi/lo [C][R] bf16
__global__ void ksplitT(const float* __restrict__ src, ushort* __restrict__ hi,
                        ushort* __restrict__ lo, int R, int C) {
    __shared__ float tile[32][33];
    const int tc = blockIdx.x * 32, tr = blockIdx.y * 32;
    const int lx = threadIdx.x, ly = threadIdx.y;      // 32 x 8
    for (int i = 0; i < 32; i += 8) {
        int r = tr + ly + i, c = tc + lx;
        tile[ly + i][lx] = (r < R && c < C) ? src[(size_t)r * C + c] : 0.f;
    }
    __syncthreads();
    for (int i = 0; i < 32; i += 8) {
        int c = tc + ly + i, r = tr + lx;              // out row = c, col = r
        if (c < C && r < R) {
            float f = tile[lx][ly + i];
            ushort h = f2bf(f);
            hi[(size_t)c * R + r] = h;
            lo[(size_t)c * R + r] = f2bf(f - bf2f(h));
        }
    }
}

// ---------------- K1: LN1 + x = ln1 @ W_att + a_s/a_d ----------------
__global__ __launch_bounds__(256) void k1_ln_proj(
    const float* __restrict__ nf, const float* __restrict__ g, const float* __restrict__ b,
    const float* __restrict__ W, const float* __restrict__ asrc, const float* __restrict__ adst,
    float* __restrict__ x, float* __restrict__ a_s, float* __restrict__ a_d,
    int n, int npb) {
    __shared__ float WT[DD][132];
    __shared__ float lnrow[4][DD];
    __shared__ float psum[16];
    const int tid = threadIdx.x;
    for (int i = tid; i < DD * DD; i += 256) {
        int k = i >> 7, c = i & 127;
        WT[c][k] = W[i];
    }
    const int t  = tid & 127;
    const int p  = tid >> 7;
    const int wv = tid >> 6;
    const float gt = g[t], bt = b[t];
    const float at_s = asrc[t], at_d = adst[t];
    const int base = blockIdx.x * npb;
    __syncthreads();
    for (int it = 0; it < npb; it += 4) {
        const int n0 = base + it + 2 * p;
        const int n1 = n0 + 1;
        const bool v0 = n0 < n, v1 = n1 < n;
        float val0 = v0 ? nf[(size_t)n0 * DD + t] : 0.f;
        float val1 = v1 ? nf[(size_t)n1 * DD + t] : 0.f;
        float s0 = val0, s1 = val1;
        #pragma unroll
        for (int o = 32; o >= 1; o >>= 1) { s0 += __shfl_xor(s0, o); s1 += __shfl_xor(s1, o); }
        if ((tid & 63) == 0) { psum[wv] = s0; psum[8 + wv] = s1; }
        __syncthreads();
        const float mean0 = (psum[2 * p] + psum[2 * p + 1]) * (1.f / DD);
        const float mean1 = (psum[8 + 2 * p] + psum[8 + 2 * p + 1]) * (1.f / DD);
        __syncthreads();
        const float d0 = val0 - mean0, d1 = val1 - mean1;
        s0 = d0 * d0; s1 = d1 * d1;
        #pragma unroll
        for (int o = 32; o >= 1; o >>= 1) { s0 += __shfl_xor(s0, o); s1 += __shfl_xor(s1, o); }
        if ((tid & 63) == 0) { psum[wv] = s0; psum[8 + wv] = s1; }
        __syncthreads();
        const float var0 = (psum[2 * p] + psum[2 * p + 1]) * (1.f / (DD - 1));
        const float var1 = (psum[8 + 2 * p] + psum[8 + 2 * p + 1]) * (1.f / (DD - 1));
        const float i0 = 1.f / (sqrtf(var0) + EPS);
        const float i1 = 1.f / (sqrtf(var1) + EPS);
        lnrow[2 * p][t]     = gt * d0 * i0 + bt;
        lnrow[2 * p + 1][t] = gt * d1 * i1 + bt;
        __syncthreads();
        float acc0 = 0.f, acc1 = 0.f;
        const float4* lr0 = (const float4*)lnrow[2 * p];
        const float4* lr1 = (const float4*)lnrow[2 * p + 1];
        #pragma unroll 8
        for (int k4 = 0; k4 < 32; ++k4) {
            float4 w4 = *(const float4*)&WT[t][k4 * 4];
            float4 l0 = lr0[k4];
            float4 l1 = lr1[k4];
            acc0 = fmaf(w4.x, l0.x, fmaf(w4.y, l0.y, fmaf(w4.z, l0.z, fmaf(w4.w, l0.w, acc0))));
            acc1 = fmaf(w4.x, l1.x, fmaf(w4.y, l1.y, fmaf(w4.z, l1.z, fmaf(w4.w, l1.w, acc1))));
        }
        if (v0) x[(size_t)n0 * DD + t] = acc0;
        if (v1) x[(size_t)n1 * DD + t] = acc1;
        float as0 = acc0 * at_s, as1 = acc1 * at_s;
        float ad0 = acc0 * at_d, ad1 = acc1 * at_d;
        #pragma unroll
        for (int o = 8; o >= 1; o >>= 1) {
            as0 += __shfl_xor(as0, o); as1 += __shfl_xor(as1, o);
            ad0 += __shfl_xor(ad0, o); ad1 += __shfl_xor(ad1, o);
        }
        if ((t & 15) == 0) {
            int h = t >> 4;
            if (v0) { a_s[n0 * HH + h] = as0; a_d[n0 * HH + h] = ad0; }
            if (v1) { a_s[n1 * HH + h] = as1; a_d[n1 * HH + h] = ad1; }
        }
        __syncthreads();
    }
}

// ---------------- K2: in-degree count ----------------
__global__ void k2_deg(const int* __restrict__ ei, int* __restrict__ deg, int E) {
    int e = blockIdx.x * blockDim.x + threadIdx.x;
    if (e < E) atomicAdd(&deg[ei[E + e]], 1);
}

// ---------------- K3a/b/c: hierarchical exclusive scan ----------------
__global__ __launch_bounds__(1024) void k3a(const int* __restrict__ deg, int* __restrict__ incl,
                                            int* __restrict__ bsum, int n) {
    __shared__ int wsum[16];
    const int b = blockIdx.x, t = threadIdx.x;
    const int i0 = b * 4096 + t * 4;
    int4 v = make_int4(0, 0, 0, 0);
    if (i0 + 3 < n) v = *(const int4*)&deg[i0];
    else {
        int* vp = (int*)&v;
        for (int q = 0; q < 4; ++q) vp[q] = (i0 + q < n) ? deg[i0 + q] : 0;
    }
    const int s1 = v.x, s2 = s1 + v.y, s3 = s2 + v.z, s4 = s3 + v.w;
    const int lane = t & 63, wv = t >> 6;
    int xx = s4;
    #pragma unroll
    for (int off = 1; off < 64; off <<= 1) {
        int y = __shfl_up(xx, off);
        if (lane >= off) xx += y;
    }
    if (lane == 63) wsum[wv] = xx;
    __syncthreads();
    if (wv == 0) {
        int y = (lane < 16) ? wsum[lane] : 0;
        #pragma unroll
        for (int off = 1; off < 16; off <<= 1) {
            int z = __shfl_up(y, off);
            if (lane >= off) y += z;
        }
        if (lane < 16) wsum[lane] = y;
    }
    __syncthreads();
    const int wbase = (wv == 0) ? 0 : wsum[wv - 1];
    const int excl = xx - s4 + wbase;
    if (i0 < n) {
        int4 o = make_int4(excl + s1, excl + s2, excl + s3, excl + s4);
        if (i0 + 3 < n) *(int4*)&incl[i0] = o;
        else {
            int* op = (int*)&o;
            for (int q = 0; q < 4; ++q) if (i0 + q < n) incl[i0 + q] = op[q];
        }
    }
    if (t == 1023) bsum[b] = wbase + xx;
}

__global__ void k3b(int* __restrict__ bsum, int nb) {
    int t = threadIdx.x;
    int v = (t < nb) ? bsum[t] : 0;
    #pragma unroll
    for (int off = 1; off < 64; off <<= 1) {
        int y = __shfl_up(v, off);
        if (t >= off) v += y;
    }
    if (t < nb) bsum[t] = v;   // inclusive
}

__global__ void k3c(const int* __restrict__ incl, const int* __restrict__ bsum,
                    const int* __restrict__ deg, int* __restrict__ row_ptr,
                    int* __restrict__ cursor, int n) {
    int i = blockIdx.x * blockDim.x + threadIdx.x;
    if (i < n) {
        int b = i >> 12;
        int base = b ? bsum[b - 1] : 0;
        int inc = incl[i] + base;
        row_ptr[i + 1] = inc;
        cursor[i] = inc - deg[i];
        if (i == 0) row_ptr[0] = 0;
    }
}

// ---------------- K4: scatter src ids into CSR ----------------
__global__ void k4_scatter(const int* __restrict__ ei, int* __restrict__ cursor,
                           int* __restrict__ col_src, int E) {
    int e = blockIdx.x * blockDim.x + threadIdx.x;
    if (e < E) {
        int dst = ei[E + e];
        int pos = atomicAdd(&cursor[dst], 1);
        col_src[pos] = ei[e];
    }
}

// ---------------- K5: per-dst online-softmax gather + residual + LN2 ----------------
__global__ __launch_bounds__(256) void k5_gather(
    const float* __restrict__ x, const float* __restrict__ a_s, const float* __restrict__ a_d,
    const int* __restrict__ row_ptr, const int* __restrict__ col_src,
    const float* __restrict__ nf, const float* __restrict__ bias_att,
    const float* __restrict__ ln2g, const float* __restrict__ ln2b,
    float* __restrict__ nf1, float* __restrict__ h2, int n) {
    const int w = (blockIdx.x * blockDim.x + threadIdx.x) >> 6;
    if (w >= n) return;
    const int lane = threadIdx.x & 63;
    const int h = lane >> 3;
    const int c0 = lane * 2;
    const float ad = a_d[w * HH + h];
    float e = a_s[w * HH + h] + ad;
    e = e > 0.f ? e : SLOPE * e;
    float m = e, denom = 1.f;
    float2 xv = *(const float2*)&x[(size_t)w * DD + c0];
    float acc0 = xv.x, acc1 = xv.y;
    const int beg = row_ptr[w], end = row_ptr[w + 1];
    int j = beg;
#define UPD(ev_, xs_) { float ev = (ev_) + ad; ev = ev > 0.f ? ev : SLOPE * ev;            \
        float nm = fmaxf(m, ev); float sc = __expf(m - nm); float pp = __expf(ev - nm);    \
        denom = denom * sc + pp; acc0 = acc0 * sc + xs_.x * pp; acc1 = acc1 * sc + xs_.y * pp; m = nm; }
    for (; j + 4 <= end; j += 4) {
        const int s0 = col_src[j], s1 = col_src[j + 1], s2 = col_src[j + 2], s3 = col_src[j + 3];
        const float e0 = a_s[s0 * HH + h], e1 = a_s[s1 * HH + h];
        const float e2 = a_s[s2 * HH + h], e3 = a_s[s3 * HH + h];
        const float2 x0 = *(const float2*)&x[(size_t)s0 * DD + c0];
        const float2 x1 = *(const float2*)&x[(size_t)s1 * DD + c0];
        const float2 x2 = *(const float2*)&x[(size_t)s2 * DD + c0];
        const float2 x3 = *(const float2*)&x[(size_t)s3 * DD + c0];
        UPD(e0, x0) UPD(e1, x1) UPD(e2, x2) UPD(e3, x3)
    }
    for (; j < end; ++j) {
        const int s0 = col_src[j];
        const float e0 = a_s[s0 * HH + h];
        const float2 x0 = *(const float2*)&x[(size_t)s0 * DD + c0];
        UPD(e0, x0)
    }
#undef UPD
    const float inv = 1.f / (denom + 1e-16f);
    float o0 = acc0 * inv + bias_att[c0]     + nf[(size_t)w * DD + c0];
    float o1 = acc1 * inv + bias_att[c0 + 1] + nf[(size_t)w * DD + c0 + 1];
    *(float2*)&nf1[(size_t)w * DD + c0] = make_float2(o0, o1);
    float s = o0 + o1;
    #pragma unroll
    for (int o = 32; o >= 1; o >>= 1) s += __shfl_xor(s, o);
    const float mean = s * (1.f / DD);
    const float d0 = o0 - mean, d1 = o1 - mean;
    float q = d0 * d0 + d1 * d1;
    #pragma unroll
    for (int o = 32; o >= 1; o >>= 1) q += __shfl_xor(q, o);
    const float var = q * (1.f / (DD - 1));
    const float iv = 1.f / (sqrtf(var) + EPS);
    float z0 = ln2g[c0] * d0 * iv + ln2b[c0];
    float z1 = ln2g[c0 + 1] * d1 * iv + ln2b[c0 + 1];
    *(float2*)&h2[(size_t)w * DD + c0] = make_float2(z0, z1);
}

// ---------------- K6: split-bf16 MFMA FFN ----------------
// out = nf1 + relu(h2@W1+b1)@W2 + b2, W pre-transposed/split: W1T[ff][k], W2T[o][k]
__global__ __launch_bounds__(256, 3) void k6_mfma(
    const float* __restrict__ h2, const float* __restrict__ nf1,
    const ushort* __restrict__ W1Thi, const ushort* __restrict__ W1Tlo,
    const ushort* __restrict__ W2Thi, const ushort* __restrict__ W2Tlo,
    const float* __restrict__ b1, const float* __restrict__ b2,
    float* __restrict__ out, int n) {
    __shared__ ushort Wb[2][8192];   // 32KB: [hi/lo] chunk, swizzled
    __shared__ float hhs[4096];      // 16KB: [64 nodes][64 ff] swizzled, wave-private rows
    const int tid = threadIdx.x;
    const int w = tid >> 6, l = tid & 63;
    const int l15 = l & 15, l4 = l >> 4;
    const int nbase = blockIdx.x * TM;

    // ---- A-frags: this wave's 16 node rows of h2, split into hi/lo bf16
    int arow = nbase + w * 16 + l15;
    if (arow >= n) arow = n - 1;                    // clamp; garbage rows never stored
    const float* ap = h2 + (size_t)arow * DD + l4 * 8;
    bf16x8 Ahi[4], Alo[4];
    #pragma unroll
    for (int s = 0; s < 4; ++s) {
        float v[8];
        *(float4*)&v[0] = *(const float4*)(ap + s * 32);
        *(float4*)&v[4] = *(const float4*)(ap + s * 32 + 4);
        bf16x8 hv, lv;
        #pragma unroll
        for (int jj = 0; jj < 8; ++jj) {
            ushort hb = f2bf(v[jj]);
            hv[jj] = (short)hb;
            lv[jj] = (short)f2bf(v[jj] - bf2f(hb));
        }
        Ahi[s] = hv; Alo[s] = lv;
    }

    f32x4 acc_o[8];
    #pragma unroll
    for (int oc = 0; oc < 8; ++oc) acc_o[oc] = (f32x4){0.f, 0.f, 0.f, 0.f};

    const int srow = tid >> 2, sq = tid & 3;        // stage-A staging: row=ff, 64B quarter
    const int brow = tid >> 1, bq = tid & 1;        // stage-B staging: row=out, 64B half

    for (int ch = 0; ch < 8; ++ch) {
        __syncthreads();                            // prev stage-B Wb reads done
        {   // stage Wb = W1T chunk (ff rows [ch*64,+64), 128 k each), swizzled
            const size_t gg = (size_t)(ch * 64 + srow) * DD + sq * 32;
            #pragma unroll
            for (int u = 0; u < 4; ++u) {
                int byte = (srow * 256 + sq * 64 + u * 16) ^ ((srow & 7) << 4);
                *(bf16x8*)((char*)Wb[0] + byte) = *(const bf16x8*)(W1Thi + gg + u * 8);
                *(bf16x8*)((char*)Wb[1] + byte) = *(const bf16x8*)(W1Tlo + gg + u * 8);
            }
        }
        __syncthreads();
        // ---- stage A: hh_chunk[16 nodes][64 ff] per wave
        #pragma unroll
        for (int tc = 0; tc < 4; ++tc) {
            f32x4 a = (f32x4){0.f, 0.f, 0.f, 0.f};
            #pragma unroll
            for (int s = 0; s < 4; ++s) {
                const int row = tc * 16 + l15;
                const int byte = (row * 256 + s * 64 + l4 * 16) ^ ((row & 7) << 4);
                bf16x8 bh = *(const bf16x8*)((char*)Wb[0] + byte);
                bf16x8 bl = *(const bf16x8*)((char*)Wb[1] + byte);
                a = __builtin_amdgcn_mfma_f32_16x16x32_bf16(Ahi[s], bh, a, 0, 0, 0);
                a = __builtin_amdgcn_mfma_f32_16x16x32_bf16(Alo[s], bh, a, 0, 0, 0);
                a = __builtin_amdgcn_mfma_f32_16x16x32_bf16(Ahi[s], bl, a, 0, 0, 0);
            }
            // bias + relu + write hh (wave-private rows -> no barrier)
            const float bias = b1[ch * 64 + tc * 16 + l15];
            #pragma unroll
            for (int i = 0; i < 4; ++i) {
                float hvv = fmaxf(a[i] + bias, 0.f);
                const int row = w * 16 + l4 * 4 + i;
                const int byte = (row * 256 + (tc * 16 + l15) * 4) ^ ((row & 7) << 4);
                *(float*)((char*)hhs + byte) = hvv;
            }
        }
        __syncthreads();                            // stage-A Wb reads done
        {   // stage Wb = W2T chunk (out rows 0..127, k in [ch*64,+64)), swizzled
            const size_t gg = (size_t)brow * DFF + ch * 64 + bq * 32;
            #pragma unroll
            for (int u = 0; u < 4; ++u) {
                int byte = (brow * 128 + bq * 64 + u * 16) ^ ((brow & 7) << 4);
                *(bf16x8*)((char*)Wb[0] + byte) = *(const bf16x8*)(W2Thi + gg + u * 8);
                *(bf16x8*)((char*)Wb[1] + byte) = *(const bf16x8*)(W2Tlo + gg + u * 8);
            }
        }
        // ---- build stage-B A-frags from own hh rows (overlaps W2 staging)
        bf16x8 Phi[2], Plo[2];
        #pragma unroll
        for (int cs = 0; cs < 2; ++cs) {
            const int row = w * 16 + l15;
            const int base = row * 256 + (cs * 32 + l4 * 8) * 4;
            const int msk = (row & 7) << 4;
            float v[8];
            *(float4*)&v[0] = *(const float4*)((char*)hhs + (base ^ msk));
            *(float4*)&v[4] = *(const float4*)((char*)hhs + ((base + 16) ^ msk));
            bf16x8 hv, lv;
            #pragma unroll
            for (int jj = 0; jj < 8; ++jj) {
                ushort hb = f2bf(v[jj]);
                hv[jj] = (short)hb;
                lv[jj] = (short)f2bf(v[jj] - bf2f(hb));
            }
            Phi[cs] = hv; Plo[cs] = lv;
        }
        __syncthreads();                            // W2 staged
        #pragma unroll
        for (int oc = 0; oc < 8; ++oc) {
            #pragma unroll
            for (int cs = 0; cs < 2; ++cs) {
                const int row = oc * 16 + l15;
                const int byte = (row * 128 + cs * 64 + l4 * 16) ^ ((row & 7) << 4);
                bf16x8 bh = *(const bf16x8*)((char*)Wb[0] + byte);
                bf16x8 bl = *(const bf16x8*)((char*)Wb[1] + byte);
                acc_o[oc] = __builtin_amdgcn_mfma_f32_16x16x32_bf16(Phi[cs], bh, acc_o[oc], 0, 0, 0);
                acc_o[oc] = __builtin_amdgcn_mfma_f32_16x16x32_bf16(Plo[cs], bh, acc_o[oc], 0, 0, 0);
                acc_o[oc] = __builtin_amdgcn_mfma_f32_16x16x32_bf16(Phi[cs], bl, acc_o[oc], 0, 0, 0);
            }
        }
    }
    // ---- epilogue: + b2 + residual
    #pragma unroll
    for (int oc = 0; oc < 8; ++oc) {
        const int col = oc * 16 + l15;
        const float b2v = b2[col];
        #pragma unroll
        for (int i = 0; i < 4; ++i) {
            const int node = nbase + w * 16 + l4 * 4 + i;
            if (node < n)
                out[(size_t)node * DD + col] = acc_o[oc][i] + b2v + nf1[(size_t)node * DD + col];
        }
    }
}

extern "C" void kernel_launch(void* const* d_in, const int* in_sizes, int n_in,
                              void* d_out, int out_size, void* d_ws, size_t ws_size,
                              hipStream_t stream) {
    const float* nf       = (const float*)d_in[0];
    const int*   ei       = (const int*)d_in[1];
    const float* ln1_g    = (const float*)d_in[2];
    const float* ln1_b    = (const float*)d_in[3];
    const float* W_att    = (const float*)d_in[4];
    const float* att_src  = (const float*)d_in[5];
    const float* att_dst  = (const float*)d_in[6];
    const float* bias_att = (const float*)d_in[7];
    const float* ln2_g    = (const float*)d_in[8];
    const float* ln2_b    = (const float*)d_in[9];
    const float* W1       = (const float*)d_in[10];
    const float* b1       = (const float*)d_in[11];
    const float* W2       = (const float*)d_in[12];
    const float* b2       = (const float*)d_in[13];
    const int n = in_sizes[0] / DD;
    const int E = in_sizes[1] / 2;

    char* ws = (char*)d_ws;
    size_t off = 0;
    auto alloc = [&](size_t bytes) {
        off = (off + 255) & ~(size_t)255;
        char* p = ws + off;
        off += bytes;
        return p;
    };
    float*  x       = (float*)alloc((size_t)n * DD * 4);
    float*  a_s     = (float*)alloc((size_t)n * HH * 4);
    float*  a_d     = (float*)alloc((size_t)n * HH * 4);
    float*  nf1     = (float*)alloc((size_t)n * DD * 4);
    float*  h2      = (float*)alloc((size_t)n * DD * 4);
    int*    row_ptr = (int*)alloc((size_t)(n + 1) * 4);
    int*    cursor  = (int*)alloc((size_t)n * 4);
    int*    deg     = (int*)alloc((size_t)n * 4);
    int*    incl    = (int*)alloc((size_t)n * 4);
    int*    bsum    = (int*)alloc(64 * 4);
    int*    col_src = (int*)alloc((size_t)E * 4);
    ushort* W1Thi   = (ushort*)alloc((size_t)DFF * DD * 2);
    ushort* W1Tlo   = (ushort*)alloc((size_t)DFF * DD * 2);
    ushort* W2Thi   = (ushort*)alloc((size_t)DD * DFF * 2);
    ushort* W2Tlo   = (ushort*)alloc((size_t)DD * DFF * 2);
    (void)ws_size; (void)n_in; (void)out_size;

    const int npb = 64;
    const int nb3 = (n + 4095) / 4096;

    ksplitT<<<dim3(DFF / 32, DD / 32), dim3(32, 8), 0, stream>>>(W1, W1Thi, W1Tlo, DD, DFF);
    ksplitT<<<dim3(DD / 32, DFF / 32), dim3(32, 8), 0, stream>>>(W2, W2Thi, W2Tlo, DFF, DD);
    kzero<<<(n + 255) / 256, 256, 0, stream>>>(deg, n);
    k1_ln_proj<<<(n + npb - 1) / npb, 256, 0, stream>>>(nf, ln1_g, ln1_b, W_att, att_src, att_dst,
                                                        x, a_s, a_d, n, npb);
    k2_deg<<<(E + 255) / 256, 256, 0, stream>>>(ei, deg, E);
    k3a<<<nb3, 1024, 0, stream>>>(deg, incl, bsum, n);
    k3b<<<1, 64, 0, stream>>>(bsum, nb3);
    k3c<<<(n + 255) / 256, 256, 0, stream>>>(incl, bsum, deg, row_ptr, cursor, n);
    k4_scatter<<<(E + 255) / 256, 256, 0, stream>>>(ei, cursor, col_src, E);
    k5_gather<<<(n + 3) / 4, 256, 0, stream>>>(x, a_s, a_d, row_ptr, col_src, nf, bias_att,
                                               ln2_g, ln2_b, nf1, h2, n);
    k6_mfma<<<(n + TM - 1) / TM, 256, 0, stream>>>(h2, nf1, W1Thi, W1Tlo, W2Thi, W2Tlo,
                                                   b1, b2, (float*)d_out, n);
}

// Round 3
// 427.825 us; speedup vs baseline: 1.9829x; 1.1190x over previous
//
#include <hip/hip_runtime.h>

#define DD 128
#define HH 8
#define DFF 512
#define EPS 1e-6f
#define SLOPE 0.2f
#define TM 64

typedef float f32x4 __attribute__((ext_vector_type(4)));
typedef short bf16x8 __attribute__((ext_vector_type(8)));

__device__ __forceinline__ ushort f2bf(float f) {
    unsigned u = __float_as_uint(f);
    return (ushort)((u + 0x7FFFu + ((u >> 16) & 1u)) >> 16);   // RNE
}
__device__ __forceinline__ float bf2f(ushort h) {
    return __uint_as_float(((unsigned)h) << 16);
}

// ---------------- zero int buffer ----------------
__global__ void kzero(int* __restrict__ p, int n) {
    int i = blockIdx.x * blockDim.x + threadIdx.x;
    if (i < n) p[i] = 0;
}

// ---------------- prep: transpose + split fp32 -> bf16 hi/lo ----------------
// src [R][C] fp32  ->  hi/lo [C][R] bf16 (row stride R)
__global__ void ksplitT(const float* __restrict__ src, ushort* __restrict__ hi,
                        ushort* __restrict__ lo, int R, int C) {
    __shared__ float tile[32][33];
    const int tc = blockIdx.x * 32, tr = blockIdx.y * 32;
    const int lx = threadIdx.x, ly = threadIdx.y;      // 32 x 8
    for (int i = 0; i < 32; i += 8) {
        int r = tr + ly + i, c = tc + lx;
        tile[ly + i][lx] = (r < R && c < C) ? src[(size_t)r * C + c] : 0.f;
    }
    __syncthreads();
    for (int i = 0; i < 32; i += 8) {
        int c = tc + ly + i, r = tr + lx;
        if (c < C && r < R) {
            float f = tile[lx][ly + i];
            ushort h = f2bf(f);
            hi[(size_t)c * R + r] = h;
            lo[(size_t)c * R + r] = f2bf(f - bf2f(h));
        }
    }
}

// ---------------- prep: attention weight fold ----------------
// Was[k][h] = sum_dh W[k][h*16+dh] * asrc[h*16+dh]  -> rows 128..135 of WA (stride 128)
// Wad[k][h] -> rows 136..143
__global__ void kattw(const float* __restrict__ W, const float* __restrict__ asrc,
                      const float* __restrict__ adst, ushort* __restrict__ hi,
                      ushort* __restrict__ lo) {
    const int k = threadIdx.x;   // 128 threads
    for (int h = 0; h < HH; ++h) {
        float s1 = 0.f, s2 = 0.f;
        #pragma unroll
        for (int dh = 0; dh < 16; ++dh) {
            float w = W[k * DD + h * 16 + dh];
            s1 = fmaf(w, asrc[h * 16 + dh], s1);
            s2 = fmaf(w, adst[h * 16 + dh], s2);
        }
        ushort h1 = f2bf(s1);
        hi[(128 + h) * DD + k] = h1;
        lo[(128 + h) * DD + k] = f2bf(s1 - bf2f(h1));
        ushort h2 = f2bf(s2);
        hi[(136 + h) * DD + k] = h2;
        lo[(136 + h) * DD + k] = f2bf(s2 - bf2f(h2));
    }
}

// ---------------- K1: LN1 + [x | a_s | a_d] = ln1 @ [W_att | Was | Wad] via MFMA ----------------
// LDS-free: W frags read straight from L2 (72KB total, fully cached).
__global__ __launch_bounds__(256) void k1_mfma(
    const float* __restrict__ nf, const float* __restrict__ g, const float* __restrict__ b,
    const ushort* __restrict__ WAhi, const ushort* __restrict__ WAlo,
    float* __restrict__ x, float* __restrict__ a_s, float* __restrict__ a_d, int n) {
    const int tid = threadIdx.x;
    const int w = tid >> 6, l = tid & 63;
    const int l15 = l & 15, l4 = l >> 4;
    const int nbase = blockIdx.x * TM;
    int arow = nbase + w * 16 + l15;
    if (arow >= n) arow = n - 1;                    // clamp; tail writes guarded

    // load this row's 32 elements (4 frags x 8)
    float v[4][8];
    const float* ap = nf + (size_t)arow * DD + l4 * 8;
    #pragma unroll
    for (int s = 0; s < 4; ++s) {
        *(float4*)&v[s][0] = *(const float4*)(ap + s * 32);
        *(float4*)&v[s][4] = *(const float4*)(ap + s * 32 + 4);
    }
    // LN: row is spread over lanes {l15, l15+16, l15+32, l15+48}
    float sum = 0.f;
    #pragma unroll
    for (int s = 0; s < 4; ++s)
        #pragma unroll
        for (int j = 0; j < 8; ++j) sum += v[s][j];
    sum += __shfl_xor(sum, 16);
    sum += __shfl_xor(sum, 32);
    const float mean = sum * (1.f / DD);
    float qs = 0.f;
    #pragma unroll
    for (int s = 0; s < 4; ++s)
        #pragma unroll
        for (int j = 0; j < 8; ++j) { float d = v[s][j] - mean; qs += d * d; }
    qs += __shfl_xor(qs, 16);
    qs += __shfl_xor(qs, 32);
    const float iv = 1.f / (sqrtf(qs * (1.f / (DD - 1))) + EPS);

    // normalize + split to bf16 hi/lo
    bf16x8 Ahi[4], Alo[4];
    #pragma unroll
    for (int s = 0; s < 4; ++s) {
        const int k0 = s * 32 + l4 * 8;
        float gv[8], bv[8];
        *(float4*)&gv[0] = *(const float4*)(g + k0);
        *(float4*)&gv[4] = *(const float4*)(g + k0 + 4);
        *(float4*)&bv[0] = *(const float4*)(b + k0);
        *(float4*)&bv[4] = *(const float4*)(b + k0 + 4);
        bf16x8 hv, lv;
        #pragma unroll
        for (int j = 0; j < 8; ++j) {
            float f = fmaf(gv[j], (v[s][j] - mean) * iv, bv[j]);
            ushort hb = f2bf(f);
            hv[j] = (short)hb;
            lv[j] = (short)f2bf(f - bf2f(hb));
        }
        Ahi[s] = hv; Alo[s] = lv;
    }

    // 9 col-tiles: 0..7 = x cols, 8 = [a_s(8) | a_d(8)]
    #pragma unroll
    for (int oc = 0; oc < 9; ++oc) {
        f32x4 acc = (f32x4){0.f, 0.f, 0.f, 0.f};
        const ushort* bp = WAhi + (size_t)(oc * 16 + l15) * DD + l4 * 8;
        const ushort* lp = WAlo + (size_t)(oc * 16 + l15) * DD + l4 * 8;
        #pragma unroll
        for (int s = 0; s < 4; ++s) {
            bf16x8 bh = *(const bf16x8*)(bp + s * 32);
            bf16x8 bl = *(const bf16x8*)(lp + s * 32);
            acc = __builtin_amdgcn_mfma_f32_16x16x32_bf16(Ahi[s], bh, acc, 0, 0, 0);
            acc = __builtin_amdgcn_mfma_f32_16x16x32_bf16(Alo[s], bh, acc, 0, 0, 0);
            acc = __builtin_amdgcn_mfma_f32_16x16x32_bf16(Ahi[s], bl, acc, 0, 0, 0);
        }
        #pragma unroll
        for (int i = 0; i < 4; ++i) {
            const int node = nbase + w * 16 + l4 * 4 + i;
            if (node < n) {
                if (oc < 8) x[(size_t)node * DD + oc * 16 + l15] = acc[i];
                else if (l15 < 8) a_s[node * HH + l15] = acc[i];
                else a_d[node * HH + (l15 - 8)] = acc[i];
            }
        }
    }
}

// ---------------- K2: in-degree count ----------------
__global__ void k2_deg(const int* __restrict__ ei, int* __restrict__ deg, int E) {
    int e = blockIdx.x * blockDim.x + threadIdx.x;
    if (e < E) atomicAdd(&deg[ei[E + e]], 1);
}

// ---------------- K3a/b/c: hierarchical exclusive scan ----------------
__global__ __launch_bounds__(1024) void k3a(const int* __restrict__ deg, int* __restrict__ incl,
                                            int* __restrict__ bsum, int n) {
    __shared__ int wsum[16];
    const int b = blockIdx.x, t = threadIdx.x;
    const int i0 = b * 4096 + t * 4;
    int4 v = make_int4(0, 0, 0, 0);
    if (i0 + 3 < n) v = *(const int4*)&deg[i0];
    else {
        int* vp = (int*)&v;
        for (int q = 0; q < 4; ++q) vp[q] = (i0 + q < n) ? deg[i0 + q] : 0;
    }
    const int s1 = v.x, s2 = s1 + v.y, s3 = s2 + v.z, s4 = s3 + v.w;
    const int lane = t & 63, wv = t >> 6;
    int xx = s4;
    #pragma unroll
    for (int off = 1; off < 64; off <<= 1) {
        int y = __shfl_up(xx, off);
        if (lane >= off) xx += y;
    }
    if (lane == 63) wsum[wv] = xx;
    __syncthreads();
    if (wv == 0) {
        int y = (lane < 16) ? wsum[lane] : 0;
        #pragma unroll
        for (int off = 1; off < 16; off <<= 1) {
            int z = __shfl_up(y, off);
            if (lane >= off) y += z;
        }
        if (lane < 16) wsum[lane] = y;
    }
    __syncthreads();
    const int wbase = (wv == 0) ? 0 : wsum[wv - 1];
    const int excl = xx - s4 + wbase;
    if (i0 < n) {
        int4 o = make_int4(excl + s1, excl + s2, excl + s3, excl + s4);
        if (i0 + 3 < n) *(int4*)&incl[i0] = o;
        else {
            int* op = (int*)&o;
            for (int q = 0; q < 4; ++q) if (i0 + q < n) incl[i0 + q] = op[q];
        }
    }
    if (t == 1023) bsum[b] = wbase + xx;
}

__global__ void k3b(int* __restrict__ bsum, int nb) {
    int t = threadIdx.x;
    int v = (t < nb) ? bsum[t] : 0;
    #pragma unroll
    for (int off = 1; off < 64; off <<= 1) {
        int y = __shfl_up(v, off);
        if (t >= off) v += y;
    }
    if (t < nb) bsum[t] = v;   // inclusive
}

__global__ void k3c(const int* __restrict__ incl, const int* __restrict__ bsum,
                    const int* __restrict__ deg, int* __restrict__ row_ptr,
                    int* __restrict__ cursor, int n) {
    int i = blockIdx.x * blockDim.x + threadIdx.x;
    if (i < n) {
        int b = i >> 12;
        int base = b ? bsum[b - 1] : 0;
        int inc = incl[i] + base;
        row_ptr[i + 1] = inc;
        cursor[i] = inc - deg[i];
        if (i == 0) row_ptr[0] = 0;
    }
}

// ---------------- K4: scatter src ids into CSR ----------------
__global__ void k4_scatter(const int* __restrict__ ei, int* __restrict__ cursor,
                           int* __restrict__ col_src, int E) {
    int e = blockIdx.x * blockDim.x + threadIdx.x;
    if (e < E) {
        int dst = ei[E + e];
        int pos = atomicAdd(&cursor[dst], 1);
        col_src[pos] = ei[e];
    }
}

// ---------------- K5: per-dst online-softmax gather + residual + LN2 ----------------
__global__ __launch_bounds__(256) void k5_gather(
    const float* __restrict__ x, const float* __restrict__ a_s, const float* __restrict__ a_d,
    const int* __restrict__ row_ptr, const int* __restrict__ col_src,
    const float* __restrict__ nf, const float* __restrict__ bias_att,
    const float* __restrict__ ln2g, const float* __restrict__ ln2b,
    float* __restrict__ nf1, float* __restrict__ h2, int n) {
    const int w = (blockIdx.x * blockDim.x + threadIdx.x) >> 6;
    if (w >= n) return;
    const int lane = threadIdx.x & 63;
    const int h = lane >> 3;
    const int c0 = lane * 2;
    const float ad = a_d[w * HH + h];
    float e = a_s[w * HH + h] + ad;
    e = e > 0.f ? e : SLOPE * e;
    float m = e, denom = 1.f;
    float2 xv = *(const float2*)&x[(size_t)w * DD + c0];
    float acc0 = xv.x, acc1 = xv.y;
    const int beg = row_ptr[w], end = row_ptr[w + 1];
    int j = beg;
    // 4-edge batches: one max + 4 independent exps + single merge (short serial chain)
    for (; j + 4 <= end; j += 4) {
        const int s0 = col_src[j], s1 = col_src[j + 1], s2 = col_src[j + 2], s3 = col_src[j + 3];
        float f0 = a_s[s0 * HH + h] + ad, f1 = a_s[s1 * HH + h] + ad;
        float f2 = a_s[s2 * HH + h] + ad, f3 = a_s[s3 * HH + h] + ad;
        const float2 x0 = *(const float2*)&x[(size_t)s0 * DD + c0];
        const float2 x1 = *(const float2*)&x[(size_t)s1 * DD + c0];
        const float2 x2 = *(const float2*)&x[(size_t)s2 * DD + c0];
        const float2 x3 = *(const float2*)&x[(size_t)s3 * DD + c0];
        f0 = f0 > 0.f ? f0 : SLOPE * f0;
        f1 = f1 > 0.f ? f1 : SLOPE * f1;
        f2 = f2 > 0.f ? f2 : SLOPE * f2;
        f3 = f3 > 0.f ? f3 : SLOPE * f3;
        const float mb = fmaxf(fmaxf(f0, f1), fmaxf(f2, f3));
        const float nm = fmaxf(m, mb);
        const float sc = __expf(m - nm);
        const float p0 = __expf(f0 - nm), p1 = __expf(f1 - nm);
        const float p2 = __expf(f2 - nm), p3 = __expf(f3 - nm);
        denom = denom * sc + ((p0 + p1) + (p2 + p3));
        acc0 = acc0 * sc + (fmaf(x0.x, p0, x1.x * p1) + fmaf(x2.x, p2, x3.x * p3));
        acc1 = acc1 * sc + (fmaf(x0.y, p0, x1.y * p1) + fmaf(x2.y, p2, x3.y * p3));
        m = nm;
    }
    for (; j < end; ++j) {
        const int s0 = col_src[j];
        float ev = a_s[s0 * HH + h] + ad;
        ev = ev > 0.f ? ev : SLOPE * ev;
        const float2 x0 = *(const float2*)&x[(size_t)s0 * DD + c0];
        const float nm = fmaxf(m, ev);
        const float sc = __expf(m - nm);
        const float pp = __expf(ev - nm);
        denom = denom * sc + pp;
        acc0 = acc0 * sc + x0.x * pp;
        acc1 = acc1 * sc + x0.y * pp;
        m = nm;
    }
    const float inv = 1.f / (denom + 1e-16f);
    float o0 = acc0 * inv + bias_att[c0]     + nf[(size_t)w * DD + c0];
    float o1 = acc1 * inv + bias_att[c0 + 1] + nf[(size_t)w * DD + c0 + 1];
    *(float2*)&nf1[(size_t)w * DD + c0] = make_float2(o0, o1);
    float s = o0 + o1;
    #pragma unroll
    for (int o = 32; o >= 1; o >>= 1) s += __shfl_xor(s, o);
    const float mean = s * (1.f / DD);
    const float d0 = o0 - mean, d1 = o1 - mean;
    float q = d0 * d0 + d1 * d1;
    #pragma unroll
    for (int o = 32; o >= 1; o >>= 1) q += __shfl_xor(q, o);
    const float var = q * (1.f / (DD - 1));
    const float iv = 1.f / (sqrtf(var) + EPS);
    float z0 = ln2g[c0] * d0 * iv + ln2b[c0];
    float z1 = ln2g[c0 + 1] * d1 * iv + ln2b[c0 + 1];
    *(float2*)&h2[(size_t)w * DD + c0] = make_float2(z0, z1);
}

// ---------------- K6: split-bf16 MFMA FFN ----------------
__global__ __launch_bounds__(256, 3) void k6_mfma(
    const float* __restrict__ h2, const float* __restrict__ nf1,
    const ushort* __restrict__ W1Thi, const ushort* __restrict__ W1Tlo,
    const ushort* __restrict__ W2Thi, const ushort* __restrict__ W2Tlo,
    const float* __restrict__ b1, const float* __restrict__ b2,
    float* __restrict__ out, int n) {
    __shared__ ushort Wb[2][8192];
    __shared__ float hhs[4096];
    const int tid = threadIdx.x;
    const int w = tid >> 6, l = tid & 63;
    const int l15 = l & 15, l4 = l >> 4;
    const int nbase = blockIdx.x * TM;

    int arow = nbase + w * 16 + l15;
    if (arow >= n) arow = n - 1;
    const float* ap = h2 + (size_t)arow * DD + l4 * 8;
    bf16x8 Ahi[4], Alo[4];
    #pragma unroll
    for (int s = 0; s < 4; ++s) {
        float v[8];
        *(float4*)&v[0] = *(const float4*)(ap + s * 32);
        *(float4*)&v[4] = *(const float4*)(ap + s * 32 + 4);
        bf16x8 hv, lv;
        #pragma unroll
        for (int jj = 0; jj < 8; ++jj) {
            ushort hb = f2bf(v[jj]);
            hv[jj] = (short)hb;
            lv[jj] = (short)f2bf(v[jj] - bf2f(hb));
        }
        Ahi[s] = hv; Alo[s] = lv;
    }

    f32x4 acc_o[8];
    #pragma unroll
    for (int oc = 0; oc < 8; ++oc) acc_o[oc] = (f32x4){0.f, 0.f, 0.f, 0.f};

    const int srow = tid >> 2, sq = tid & 3;
    const int brow = tid >> 1, bq = tid & 1;

    for (int ch = 0; ch < 8; ++ch) {
        __syncthreads();
        {
            const size_t gg = (size_t)(ch * 64 + srow) * DD + sq * 32;
            #pragma unroll
            for (int u = 0; u < 4; ++u) {
                int byte = (srow * 256 + sq * 64 + u * 16) ^ ((srow & 7) << 4);
                *(bf16x8*)((char*)Wb[0] + byte) = *(const bf16x8*)(W1Thi + gg + u * 8);
                *(bf16x8*)((char*)Wb[1] + byte) = *(const bf16x8*)(W1Tlo + gg + u * 8);
            }
        }
        __syncthreads();
        #pragma unroll
        for (int tc = 0; tc < 4; ++tc) {
            f32x4 a = (f32x4){0.f, 0.f, 0.f, 0.f};
            #pragma unroll
            for (int s = 0; s < 4; ++s) {
                const int row = tc * 16 + l15;
                const int byte = (row * 256 + s * 64 + l4 * 16) ^ ((row & 7) << 4);
                bf16x8 bh = *(const bf16x8*)((char*)Wb[0] + byte);
                bf16x8 bl = *(const bf16x8*)((char*)Wb[1] + byte);
                a = __builtin_amdgcn_mfma_f32_16x16x32_bf16(Ahi[s], bh, a, 0, 0, 0);
                a = __builtin_amdgcn_mfma_f32_16x16x32_bf16(Alo[s], bh, a, 0, 0, 0);
                a = __builtin_amdgcn_mfma_f32_16x16x32_bf16(Ahi[s], bl, a, 0, 0, 0);
            }
            const float bias = b1[ch * 64 + tc * 16 + l15];
            #pragma unroll
            for (int i = 0; i < 4; ++i) {
                float hvv = fmaxf(a[i] + bias, 0.f);
                const int row = w * 16 + l4 * 4 + i;
                const int byte = (row * 256 + (tc * 16 + l15) * 4) ^ ((row & 7) << 4);
                *(float*)((char*)hhs + byte) = hvv;
            }
        }
        __syncthreads();
        {
            const size_t gg = (size_t)brow * DFF + ch * 64 + bq * 32;
            #pragma unroll
            for (int u = 0; u < 4; ++u) {
                int byte = (brow * 128 + bq * 64 + u * 16) ^ ((brow & 7) << 4);
                *(bf16x8*)((char*)Wb[0] + byte) = *(const bf16x8*)(W2Thi + gg + u * 8);
                *(bf16x8*)((char*)Wb[1] + byte) = *(const bf16x8*)(W2Tlo + gg + u * 8);
            }
        }
        bf16x8 Phi[2], Plo[2];
        #pragma unroll
        for (int cs = 0; cs < 2; ++cs) {
            const int row = w * 16 + l15;
            const int base = row * 256 + (cs * 32 + l4 * 8) * 4;
            const int msk = (row & 7) << 4;
            float v[8];
            *(float4*)&v[0] = *(const float4*)((char*)hhs + (base ^ msk));
            *(float4*)&v[4] = *(const float4*)((char*)hhs + ((base + 16) ^ msk));
            bf16x8 hv, lv;
            #pragma unroll
            for (int jj = 0; jj < 8; ++jj) {
                ushort hb = f2bf(v[jj]);
                hv[jj] = (short)hb;
                lv[jj] = (short)f2bf(v[jj] - bf2f(hb));
            }
            Phi[cs] = hv; Plo[cs] = lv;
        }
        __syncthreads();
        #pragma unroll
        for (int oc = 0; oc < 8; ++oc) {
            #pragma unroll
            for (int cs = 0; cs < 2; ++cs) {
                const int row = oc * 16 + l15;
                const int byte = (row * 128 + cs * 64 + l4 * 16) ^ ((row & 7) << 4);
                bf16x8 bh = *(const bf16x8*)((char*)Wb[0] + byte);
                bf16x8 bl = *(const bf16x8*)((char*)Wb[1] + byte);
                acc_o[oc] = __builtin_amdgcn_mfma_f32_16x16x32_bf16(Phi[cs], bh, acc_o[oc], 0, 0, 0);
                acc_o[oc] = __builtin_amdgcn_mfma_f32_16x16x32_bf16(Plo[cs], bh, acc_o[oc], 0, 0, 0);
                acc_o[oc] = __builtin_amdgcn_mfma_f32_16x16x32_bf16(Phi[cs], bl, acc_o[oc], 0, 0, 0);
            }
        }
    }
    #pragma unroll
    for (int oc = 0; oc < 8; ++oc) {
        const int col = oc * 16 + l15;
        const float b2v = b2[col];
        #pragma unroll
        for (int i = 0; i < 4; ++i) {
            const int node = nbase + w * 16 + l4 * 4 + i;
            if (node < n)
                out[(size_t)node * DD + col] = acc_o[oc][i] + b2v + nf1[(size_t)node * DD + col];
        }
    }
}

extern "C" void kernel_launch(void* const* d_in, const int* in_sizes, int n_in,
                              void* d_out, int out_size, void* d_ws, size_t ws_size,
                              hipStream_t stream) {
    const float* nf       = (const float*)d_in[0];
    const int*   ei       = (const int*)d_in[1];
    const float* ln1_g    = (const float*)d_in[2];
    const float* ln1_b    = (const float*)d_in[3];
    const float* W_att    = (const float*)d_in[4];
    const float* att_src  = (const float*)d_in[5];
    const float* att_dst  = (const float*)d_in[6];
    const float* bias_att = (const float*)d_in[7];
    const float* ln2_g    = (const float*)d_in[8];
    const float* ln2_b    = (const float*)d_in[9];
    const float* W1       = (const float*)d_in[10];
    const float* b1       = (const float*)d_in[11];
    const float* W2       = (const float*)d_in[12];
    const float* b2       = (const float*)d_in[13];
    const int n = in_sizes[0] / DD;
    const int E = in_sizes[1] / 2;

    char* ws = (char*)d_ws;
    size_t off = 0;
    auto alloc = [&](size_t bytes) {
        off = (off + 255) & ~(size_t)255;
        char* p = ws + off;
        off += bytes;
        return p;
    };
    float*  x       = (float*)alloc((size_t)n * DD * 4);
    float*  a_s     = (float*)alloc((size_t)n * HH * 4);
    float*  a_d     = (float*)alloc((size_t)n * HH * 4);
    float*  nf1     = (float*)alloc((size_t)n * DD * 4);
    float*  h2      = (float*)alloc((size_t)n * DD * 4);
    int*    row_ptr = (int*)alloc((size_t)(n + 1) * 4);
    int*    cursor  = (int*)alloc((size_t)n * 4);
    int*    deg     = (int*)alloc((size_t)n * 4);
    int*    incl    = (int*)alloc((size_t)n * 4);
    int*    bsum    = (int*)alloc(64 * 4);
    int*    col_src = (int*)alloc((size_t)E * 4);
    ushort* WAhi    = (ushort*)alloc((size_t)144 * DD * 2);   // [W_att^T | Was | Wad]
    ushort* WAlo    = (ushort*)alloc((size_t)144 * DD * 2);
    ushort* W1Thi   = (ushort*)alloc((size_t)DFF * DD * 2);
    ushort* W1Tlo   = (ushort*)alloc((size_t)DFF * DD * 2);
    ushort* W2Thi   = (ushort*)alloc((size_t)DD * DFF * 2);
    ushort* W2Tlo   = (ushort*)alloc((size_t)DD * DFF * 2);
    (void)ws_size; (void)n_in; (void)out_size;

    const int nb3 = (n + 4095) / 4096;

    ksplitT<<<dim3(DD / 32, DD / 32), dim3(32, 8), 0, stream>>>(W_att, WAhi, WAlo, DD, DD);
    kattw<<<1, 128, 0, stream>>>(W_att, att_src, att_dst, WAhi, WAlo);
    ksplitT<<<dim3(DFF / 32, DD / 32), dim3(32, 8), 0, stream>>>(W1, W1Thi, W1Tlo, DD, DFF);
    ksplitT<<<dim3(DD / 32, DFF / 32), dim3(32, 8), 0, stream>>>(W2, W2Thi, W2Tlo, DFF, DD);
    kzero<<<(n + 255) / 256, 256, 0, stream>>>(deg, n);
    k1_mfma<<<(n + TM - 1) / TM, 256, 0, stream>>>(nf, ln1_g, ln1_b, WAhi, WAlo, x, a_s, a_d, n);
    k2_deg<<<(E + 255) / 256, 256, 0, stream>>>(ei, deg, E);
    k3a<<<nb3, 1024, 0, stream>>>(deg, incl, bsum, n);
    k3b<<<1, 64, 0, stream>>>(bsum, nb3);
    k3c<<<(n + 255) / 256, 256, 0, stream>>>(incl, bsum, deg, row_ptr, cursor, n);
    k4_scatter<<<(E + 255) / 256, 256, 0, stream>>>(ei, cursor, col_src, E);
    k5_gather<<<(n + 3) / 4, 256, 0, stream>>>(x, a_s, a_d, row_ptr, col_src, nf, bias_att,
                                               ln2_g, ln2_b, nf1, h2, n);
    k6_mfma<<<(n + TM - 1) / TM, 256, 0, stream>>>(h2, nf1, W1Thi, W1Tlo, W2Thi, W2Tlo,
                                                   b1, b2, (float*)d_out, n);
}